// Round 2
// baseline (14683.043 us; speedup 1.0000x reference)
//
#include <hip/hip_runtime.h>

// Problem constants (fixed by reference setup)
#define B_ 32
#define T_ 8192
#define I_ 16
#define H_ 128
#define G_ 512   // 4*H
#define P_ 1024
#define O_ 3

__device__ __forceinline__ float sigmoid_f(float x) {
    return 1.f / (1.f + __expf(-x));
}
__device__ __forceinline__ float tanh_f(float x) {
    // 2*sigmoid(2x)-1 ; saturates correctly for large |x|
    return 2.f / (1.f + __expf(-2.f * x)) - 1.f;
}

// Barrier that only guarantees LDS visibility: drains lgkmcnt (LDS ops) then
// s_barrier, WITHOUT the vmcnt(0) drain __syncthreads() would emit. Global
// atomics/stores stay in flight across it (they are order-independent
// accumulations; dependent loads get their own compiler-inserted vmcnt waits).
__device__ __forceinline__ void lds_barrier() {
    asm volatile("s_waitcnt lgkmcnt(0)\n\ts_barrier" ::: "memory");
}

// Pin a float in a VGPR and make it opaque so the compiler cannot
// rematerialize the originating load inside the loop.
#define PIN4(v) asm volatile("" : "+v"((v).x), "+v"((v).y), "+v"((v).z), "+v"((v).w))

// One block per batch element. 512 threads = one per gate row.
// Thread g owns row g of W_ih/W_hh/biases (PyTorch gate order i,f,g,o).
// Threads 0..127 additionally own the c_j / h_j state update.
// Threads 0..383 (= o*128+j) additionally own the fused FC reduction.
__global__ __launch_bounds__(512, 2) void lstm_fused(
    const float* __restrict__ x,      // [B,T,16]
    const float* __restrict__ W_ih,   // [512,16]
    const float* __restrict__ W_hh,   // [512,128]
    const float* __restrict__ b_ih,   // [512]
    const float* __restrict__ b_hh,   // [512]
    const float* __restrict__ W_fc,   // [3,128]
    float* __restrict__ sums,         // [B,P,3]  (pre-zeroed)
    float* __restrict__ counts)       // [B,P]    (pre-zeroed)
{
    const int b   = blockIdx.x;
    const int tid = threadIdx.x;

    __shared__ float h_s[H_];        // hidden state (float4-aligned)
    __shared__ float x_s[I_];        // current timestep input
    __shared__ float g_s[G_];        // activated gates

    // ---- load weights into registers (one-time), then PIN them ----
    float4 whh[H_ / 4];
    {
        const float4* wrow = (const float4*)(W_hh + tid * H_);
        #pragma unroll
        for (int k = 0; k < H_ / 4; ++k) whh[k] = wrow[k];
    }
    #pragma unroll
    for (int k = 0; k < H_ / 4; ++k) PIN4(whh[k]);

    float4 wih[I_ / 4];
    {
        const float4* wrow = (const float4*)(W_ih + tid * I_);
        #pragma unroll
        for (int k = 0; k < I_ / 4; ++k) wih[k] = wrow[k];
    }
    #pragma unroll
    for (int k = 0; k < I_ / 4; ++k) PIN4(wih[k]);

    const float bias = b_ih[tid] + b_hh[tid];

    float wfc = 0.f;
    if (tid < O_ * H_) wfc = W_fc[tid];   // tid = o*128+j maps onto row-major [3,128]

    // ---- init state ----
    float c = 0.f;
    if (tid < H_) h_s[tid] = 0.f;
    if (tid < I_) x_s[tid] = x[(b * T_ + 0) * I_ + tid];
    __syncthreads();   // one full barrier at start is fine

    int id_prev = -1;   // photo id of previous timestep (-1 = invalid)
    float xnext = 0.f;

    for (int t = 0; t < T_; ++t) {
        // -------- region A: h_s == h_{t-1}, x_s == x_t --------

        // prefetch x_{t+1} (threads 384..399); consumed late in region B,
        // so the ~200cyc L2 latency is hidden by the matvec
        if (tid >= 384 && tid < 384 + I_ && (t + 1) < T_)
            xnext = x[(b * T_ + (t + 1)) * I_ + (tid - 384)];

        // gate pre-activation: bias + W_hh[g,:]·h + W_ih[g,:]·x_t
        float4 a4 = make_float4(0.f, 0.f, 0.f, 0.f);
        const float4* h4 = (const float4*)h_s;
        #pragma unroll
        for (int k = 0; k < H_ / 4; ++k) {
            float4 hv = h4[k];     // LDS broadcast read (all lanes same addr) — free per m136
            a4.x = fmaf(hv.x, whh[k].x, a4.x);
            a4.y = fmaf(hv.y, whh[k].y, a4.y);
            a4.z = fmaf(hv.z, whh[k].z, a4.z);
            a4.w = fmaf(hv.w, whh[k].w, a4.w);
        }
        float a = bias + (a4.x + a4.y) + (a4.z + a4.w);
        {
            const float4* x4 = (const float4*)x_s;
            #pragma unroll
            for (int k = 0; k < I_ / 4; ++k) {
                float4 xv = x4[k];
                a = fmaf(xv.x, wih[k].x, a);
                a = fmaf(xv.y, wih[k].y, a);
                a = fmaf(xv.z, wih[k].z, a);
                a = fmaf(xv.w, wih[k].w, a);
            }
        }
        // rows [0,256) = i,f sigmoid; [256,384) = g tanh; [384,512) = o sigmoid
        g_s[tid] = (tid < 256 || tid >= 384) ? sigmoid_f(a) : tanh_f(a);

        // fused FC + segment-sum for timestep t-1 (h_s still holds h_{t-1});
        // atomics are fire-and-forget — they stay in flight across lds_barrier
        if (t > 0 && id_prev >= 0) {
            if (tid < O_ * H_) {
                const int j = tid & 127, o = tid >> 7;
                float p = h_s[j] * wfc;
                #pragma unroll
                for (int off = 32; off >= 1; off >>= 1) p += __shfl_down(p, off);
                if ((tid & 63) == 0)
                    atomicAdd(&sums[(b * P_ + id_prev) * O_ + o], p);
            }
            if (tid == 0) atomicAdd(&counts[b * P_ + id_prev], 1.f);
        }

        // photo id of timestep t (x_s[2] holds it as an exact-integer float)
        {
            const int idc = (int)x_s[2];
            id_prev = (idc >= 0 && idc < P_) ? idc : -1;
        }

        lds_barrier();   // gates visible (LDS only — no vmcnt drain)

        // -------- region B: state update --------
        if (tid < H_) {
            const float gi = g_s[tid];
            const float gf = g_s[128 + tid];
            const float gg = g_s[256 + tid];
            const float go = g_s[384 + tid];
            c = fmaf(gf, c, gi * gg);
            h_s[tid] = go * tanh_f(c);
        }
        if (tid >= 384 && tid < 384 + I_ && (t + 1) < T_)
            x_s[tid - 384] = xnext;
        lds_barrier();   // h_t, x_{t+1} visible
    }

    // tail: fused FC + segment-sum for t = T-1
    if (id_prev >= 0) {
        if (tid < O_ * H_) {
            const int j = tid & 127, o = tid >> 7;
            float p = h_s[j] * wfc;
            #pragma unroll
            for (int off = 32; off >= 1; off >>= 1) p += __shfl_down(p, off);
            if ((tid & 63) == 0)
                atomicAdd(&sums[(b * P_ + id_prev) * O_ + o], p);
        }
        if (tid == 0) atomicAdd(&counts[b * P_ + id_prev], 1.f);
    }
}

// out[b,p,o] = (sums[b,p,o] + cnt*b_fc[o]) / max(cnt,1)
__global__ void finalize_kernel(const float* __restrict__ sums,
                                const float* __restrict__ counts,
                                const float* __restrict__ b_fc,
                                float* __restrict__ out)
{
    const int idx = blockIdx.x * blockDim.x + threadIdx.x;
    if (idx >= B_ * P_ * O_) return;
    const int o  = idx % O_;
    const int bp = idx / O_;
    const float cnt = counts[bp];
    const float denom = (cnt > 0.f) ? cnt : 1.f;
    out[idx] = (sums[idx] + cnt * b_fc[o]) / denom;
}

extern "C" void kernel_launch(void* const* d_in, const int* in_sizes, int n_in,
                              void* d_out, int out_size, void* d_ws, size_t ws_size,
                              hipStream_t stream) {
    const float* x    = (const float*)d_in[0];
    const float* W_ih = (const float*)d_in[1];
    const float* W_hh = (const float*)d_in[2];
    const float* b_ih = (const float*)d_in[3];
    const float* b_hh = (const float*)d_in[4];
    const float* W_fc = (const float*)d_in[5];
    const float* b_fc = (const float*)d_in[6];
    // d_in[7] = num_photos (==P_, fixed by the problem)

    float* out    = (float*)d_out;
    float* sums   = (float*)d_ws;                 // B*P*3 floats
    float* counts = sums + (size_t)B_ * P_ * O_;  // B*P floats

    const size_t ws_bytes = ((size_t)B_ * P_ * O_ + (size_t)B_ * P_) * sizeof(float);
    hipMemsetAsync(d_ws, 0, ws_bytes, stream);

    lstm_fused<<<B_, 512, 0, stream>>>(x, W_ih, W_hh, b_ih, b_hh, W_fc, sums, counts);

    const int n = B_ * P_ * O_;
    finalize_kernel<<<(n + 255) / 256, 256, 0, stream>>>(sums, counts, b_fc, out);
}

// Round 3
// 11146.107 us; speedup vs baseline: 1.3173x; 1.3173x over previous
//
#include <hip/hip_runtime.h>

// Problem constants (fixed by reference setup)
#define B_ 32
#define T_ 8192
#define I_ 16
#define H_ 128
#define G_ 512   // 4*H
#define P_ 1024
#define O_ 3

#define REP32(M) M(0) M(1) M(2) M(3) M(4) M(5) M(6) M(7) \
                 M(8) M(9) M(10) M(11) M(12) M(13) M(14) M(15) \
                 M(16) M(17) M(18) M(19) M(20) M(21) M(22) M(23) \
                 M(24) M(25) M(26) M(27) M(28) M(29) M(30) M(31)

__device__ __forceinline__ float sigmoid_f(float x) {
    return 1.f / (1.f + __expf(-x));
}
__device__ __forceinline__ float tanh_f(float x) {
    return 2.f / (1.f + __expf(-2.f * x)) - 1.f;
}

// One block per batch element. 512 threads = one per gate row (PyTorch order i,f,g,o).
// Threads 0..127 also own the c/h state update; threads 0..383 own the fused FC;
// threads 384..511 (waves 6,7) own the x-tile prefetch pipeline.
// Weights are held as 144 explicitly-named scalar floats pinned into VGPRs via
// volatile asm (asm results cannot be rematerialized -> guaranteed register
// residency across the whole T-loop; round-1/2 array versions were demoted to
// scratch, costing ~5x).
__global__ __launch_bounds__(512, 2) void lstm_fused(
    const float* __restrict__ x,      // [B,T,16]
    const float* __restrict__ W_ih,   // [512,16]
    const float* __restrict__ W_hh,   // [512,128]
    const float* __restrict__ b_ih,   // [512]
    const float* __restrict__ b_hh,   // [512]
    const float* __restrict__ W_fc,   // [3,128]
    float* __restrict__ sums,         // [B,P,3]  (fully overwritten per block)
    float* __restrict__ counts)       // [B,P]    (fully overwritten per block)
{
    const int b   = blockIdx.x;
    const int tid = threadIdx.x;

    __shared__ float h_s[H_];            // hidden state
    __shared__ float g_s[G_];            // activated gates
    __shared__ float x_tile[2][16 * I_]; // double-buffered 16-step x tile
    __shared__ float sums_lds[P_ * O_];  // per-block segment sums (12 KB)
    __shared__ float counts_lds[P_];     // per-block segment counts (4 KB)

    // ---- W_hh row -> 128 named scalars, pinned ----
    const float4* wrow = (const float4*)(W_hh + tid * H_);
    #define WDECL(n) float wa##n, wb##n, wc##n, wd##n; \
        { float4 t_ = wrow[n]; wa##n = t_.x; wb##n = t_.y; wc##n = t_.z; wd##n = t_.w; }
    REP32(WDECL)
    #define WPIN(n) asm volatile( \
        "v_mov_b32 %0, %0\n\tv_mov_b32 %1, %1\n\tv_mov_b32 %2, %2\n\tv_mov_b32 %3, %3" \
        : "+v"(wa##n), "+v"(wb##n), "+v"(wc##n), "+v"(wd##n));
    REP32(WPIN)

    // ---- W_ih row -> 16 named scalars, pinned ----
    const float4* urow = (const float4*)(W_ih + tid * I_);
    float ua0, ub0, uc0, ud0, ua1, ub1, uc1, ud1;
    float ua2, ub2, uc2, ud2, ua3, ub3, uc3, ud3;
    { float4 t_ = urow[0]; ua0 = t_.x; ub0 = t_.y; uc0 = t_.z; ud0 = t_.w; }
    { float4 t_ = urow[1]; ua1 = t_.x; ub1 = t_.y; uc1 = t_.z; ud1 = t_.w; }
    { float4 t_ = urow[2]; ua2 = t_.x; ub2 = t_.y; uc2 = t_.z; ud2 = t_.w; }
    { float4 t_ = urow[3]; ua3 = t_.x; ub3 = t_.y; uc3 = t_.z; ud3 = t_.w; }
    asm volatile("v_mov_b32 %0, %0\n\tv_mov_b32 %1, %1\n\tv_mov_b32 %2, %2\n\tv_mov_b32 %3, %3"
                 : "+v"(ua0), "+v"(ub0), "+v"(uc0), "+v"(ud0));
    asm volatile("v_mov_b32 %0, %0\n\tv_mov_b32 %1, %1\n\tv_mov_b32 %2, %2\n\tv_mov_b32 %3, %3"
                 : "+v"(ua1), "+v"(ub1), "+v"(uc1), "+v"(ud1));
    asm volatile("v_mov_b32 %0, %0\n\tv_mov_b32 %1, %1\n\tv_mov_b32 %2, %2\n\tv_mov_b32 %3, %3"
                 : "+v"(ua2), "+v"(ub2), "+v"(uc2), "+v"(ud2));
    asm volatile("v_mov_b32 %0, %0\n\tv_mov_b32 %1, %1\n\tv_mov_b32 %2, %2\n\tv_mov_b32 %3, %3"
                 : "+v"(ua3), "+v"(ub3), "+v"(uc3), "+v"(ud3));

    const float bias = b_ih[tid] + b_hh[tid];
    const float wfc  = (tid < O_ * H_) ? W_fc[tid] : 0.f;   // tid = o*128+j, row-major [3,128]

    // ---- init LDS ----
    #pragma unroll
    for (int i = tid; i < P_ * O_; i += 512) sums_lds[i] = 0.f;
    #pragma unroll
    for (int i = tid; i < P_;      i += 512) counts_lds[i] = 0.f;
    if (tid < H_) h_s[tid] = 0.f;

    const float* xb = x + (size_t)b * T_ * I_;
    float xr0 = 0.f, xr1 = 0.f;
    if (tid >= 384) {                      // tile 0 (steps 0..15)
        const int i = tid - 384;
        xr0 = xb[i]; xr1 = xb[128 + i];
        x_tile[0][i] = xr0; x_tile[0][128 + i] = xr1;
    }
    float c = 0.f;
    int id_prev = -1;
    __syncthreads();

    for (int t = 0; t < T_; ++t) {
        const int off = t & 15;
        const int buf = (t >> 4) & 1;

        // -------- region A: h_s == h_{t-1} --------

        // x prefetch pipeline (waves 6,7): load tile t+16.. at off==0,
        // commit to LDS at off==8 (8-step gap hides HBM latency from the
        // vmcnt wait the ds_write needs)
        if (tid >= 384) {
            const int i = tid - 384;
            if (off == 0 && t + 16 < T_) {
                const float* g = xb + (t + 16) * I_;
                xr0 = g[i]; xr1 = g[128 + i];
            }
            if (off == 8 && t + 8 < T_) {
                x_tile[buf ^ 1][i] = xr0; x_tile[buf ^ 1][128 + i] = xr1;
            }
        }

        // fused FC + segment accumulate for t-1 (h_s still holds h_{t-1});
        // LDS atomics only — no global traffic, nothing for vmcnt to drain
        if (t > 0 && id_prev >= 0) {
            if (tid < O_ * H_) {
                float p = h_s[tid & 127] * wfc;
                #pragma unroll
                for (int d = 32; d >= 1; d >>= 1) p += __shfl_down(p, d, 64);
                if ((tid & 63) == 0)
                    atomicAdd(&sums_lds[id_prev * O_ + (tid >> 7)], p);
            }
            if (tid == 0) atomicAdd(&counts_lds[id_prev], 1.f);
        }

        // photo id of step t (exact-integer float in channel 2)
        {
            const int idc = (int)x_tile[buf][off * I_ + 2];
            id_prev = (idc >= 0 && idc < P_) ? idc : -1;
        }

        // gate pre-activation: bias + W_hh[g,:]·h + W_ih[g,:]·x_t
        float4 a4 = make_float4(0.f, 0.f, 0.f, 0.f);
        const float4* h4 = (const float4*)h_s;
        #define WFMA(n) { float4 hv = h4[n]; \
            a4.x = fmaf(hv.x, wa##n, a4.x); a4.y = fmaf(hv.y, wb##n, a4.y); \
            a4.z = fmaf(hv.z, wc##n, a4.z); a4.w = fmaf(hv.w, wd##n, a4.w); }
        REP32(WFMA)
        float a = bias + (a4.x + a4.y) + (a4.z + a4.w);
        {
            const float4* x4 = (const float4*)&x_tile[buf][off * I_];
            float4 xv;
            xv = x4[0]; a = fmaf(xv.x, ua0, a); a = fmaf(xv.y, ub0, a);
                        a = fmaf(xv.z, uc0, a); a = fmaf(xv.w, ud0, a);
            xv = x4[1]; a = fmaf(xv.x, ua1, a); a = fmaf(xv.y, ub1, a);
                        a = fmaf(xv.z, uc1, a); a = fmaf(xv.w, ud1, a);
            xv = x4[2]; a = fmaf(xv.x, ua2, a); a = fmaf(xv.y, ub2, a);
                        a = fmaf(xv.z, uc2, a); a = fmaf(xv.w, ud2, a);
            xv = x4[3]; a = fmaf(xv.x, ua3, a); a = fmaf(xv.y, ub3, a);
                        a = fmaf(xv.z, uc3, a); a = fmaf(xv.w, ud3, a);
        }
        // rows [0,256)=i,f sigmoid; [256,384)=g tanh; [384,512)=o sigmoid
        g_s[tid] = (tid < 256 || tid >= 384) ? sigmoid_f(a) : tanh_f(a);

        __syncthreads();   // gates visible

        // -------- region B: state update --------
        if (tid < H_) {
            const float gi = g_s[tid];
            const float gf = g_s[128 + tid];
            const float gg = g_s[256 + tid];
            const float go = g_s[384 + tid];
            c = fmaf(gf, c, gi * gg);
            h_s[tid] = go * tanh_f(c);
        }
        __syncthreads();   // h_t visible
    }

    // tail: FC + segment accumulate for t = T-1
    if (id_prev >= 0) {
        if (tid < O_ * H_) {
            float p = h_s[tid & 127] * wfc;
            #pragma unroll
            for (int d = 32; d >= 1; d >>= 1) p += __shfl_down(p, d, 64);
            if ((tid & 63) == 0)
                atomicAdd(&sums_lds[id_prev * O_ + (tid >> 7)], p);
        }
        if (tid == 0) atomicAdd(&counts_lds[id_prev], 1.f);
    }
    __syncthreads();

    // ---- writeback (block b owns slice b exclusively; plain stores) ----
    float* sums_g = sums + (size_t)b * P_ * O_;
    #pragma unroll
    for (int i = tid; i < P_ * O_; i += 512) sums_g[i] = sums_lds[i];
    float* cnt_g = counts + (size_t)b * P_;
    #pragma unroll
    for (int i = tid; i < P_; i += 512) cnt_g[i] = counts_lds[i];
}

// out[b,p,o] = (sums[b,p,o] + cnt*b_fc[o]) / max(cnt,1)
__global__ void finalize_kernel(const float* __restrict__ sums,
                                const float* __restrict__ counts,
                                const float* __restrict__ b_fc,
                                float* __restrict__ out)
{
    const int idx = blockIdx.x * blockDim.x + threadIdx.x;
    if (idx >= B_ * P_ * O_) return;
    const int o  = idx % O_;
    const int bp = idx / O_;
    const float cnt = counts[bp];
    const float denom = (cnt > 0.f) ? cnt : 1.f;
    out[idx] = (sums[idx] + cnt * b_fc[o]) / denom;
}

extern "C" void kernel_launch(void* const* d_in, const int* in_sizes, int n_in,
                              void* d_out, int out_size, void* d_ws, size_t ws_size,
                              hipStream_t stream) {
    const float* x    = (const float*)d_in[0];
    const float* W_ih = (const float*)d_in[1];
    const float* W_hh = (const float*)d_in[2];
    const float* b_ih = (const float*)d_in[3];
    const float* b_hh = (const float*)d_in[4];
    const float* W_fc = (const float*)d_in[5];
    const float* b_fc = (const float*)d_in[6];
    // d_in[7] = num_photos (==P_, fixed by the problem)

    float* out    = (float*)d_out;
    float* sums   = (float*)d_ws;                 // B*P*3 floats
    float* counts = sums + (size_t)B_ * P_ * O_;  // B*P floats
    // sums/counts are fully overwritten by lstm_fused (disjoint per-block
    // slices) — no memset needed.

    lstm_fused<<<B_, 512, 0, stream>>>(x, W_ih, W_hh, b_ih, b_hh, W_fc, sums, counts);

    const int n = B_ * P_ * O_;
    finalize_kernel<<<(n + 255) / 256, 256, 0, stream>>>(sums, counts, b_fc, out);
}

// Round 4
// 6871.416 us; speedup vs baseline: 2.1368x; 1.6221x over previous
//
#include <hip/hip_runtime.h>

// Problem constants (fixed by reference setup)
#define B_ 32
#define T_ 8192
#define I_ 16
#define H_ 128
#define P_ 1024
#define O_ 3

// ---- macro machinery -------------------------------------------------------
#define REP8(M) M(0) M(1) M(2) M(3) M(4) M(5) M(6) M(7)
#define FORG(M, n) M(0, n) M(1, n) M(2, n) M(3, n)
#define FORALLW(M) FORG(M,0) FORG(M,1) FORG(M,2) FORG(M,3) \
                   FORG(M,4) FORG(M,5) FORG(M,6) FORG(M,7)

// DPP quad-perm (kc lanes form quads): pure-VALU cross-lane, no LDS pipe.
#define DPPF(v, ctrl) \
    __int_as_float(__builtin_amdgcn_mov_dpp(__float_as_int(v), (ctrl), 0xF, 0xF, true))
// ds_swizzle xor-lane (BitMode): xor4=0x101F xor8=0x201F xor16=0x401F
#define SWZF(v, imm) \
    __int_as_float(__builtin_amdgcn_ds_swizzle(__float_as_int(v), (imm)))

__device__ __forceinline__ float tanh_f(float x) {
    return 2.f / (1.f + __expf(-2.f * x)) - 1.f;
}

// LDS-only barrier: drain DS ops, s_barrier — WITHOUT the vmcnt(0) drain
// __syncthreads() emits. The only in-flight global ops are the x-prefetch
// loads (consumed via register dependency -> compiler inserts its own vmcnt
// wait at the consumer). Correctness needs only LDS visibility here.
__device__ __forceinline__ void lds_barrier() {
    asm volatile("s_waitcnt lgkmcnt(0)\n\ts_barrier" ::: "memory");
}

// One block per batch element (one CU per serial LSTM chain).
// 512 threads, thread = (j, kc): j = unit 0..127, kc = K-chunk 0..3.
// Each thread: 4 gate rows {g*128+j} x 32-wide h-chunk [kc*32, kc*32+32)
//   -> 128 MACs but only 32 h floats of LDS reads (4x less LDS than R3).
// Quad DPP butterfly completes the 4 gate dot-products; every lane then
// redundantly computes the cell update (c replicated across the quad),
// so there is NO g_s round-trip and only ONE barrier per step.
__global__ __launch_bounds__(512) __attribute__((amdgpu_waves_per_eu(2, 2)))
void lstm_fused(
    const float* __restrict__ x,      // [B,T,16]
    const float* __restrict__ W_ih,   // [512,16]
    const float* __restrict__ W_hh,   // [512,128]
    const float* __restrict__ b_ih,   // [512]
    const float* __restrict__ b_hh,   // [512]
    const float* __restrict__ W_fc,   // [3,128]
    float* __restrict__ sums,         // [B,P,3]  (fully overwritten per block)
    float* __restrict__ counts)       // [B,P]    (fully overwritten per block)
{
    const int b   = blockIdx.x;
    const int tid = threadIdx.x;
    const int j   = tid >> 2;
    const int kc  = tid & 3;

    __shared__ __align__(16) float h_s[2][H_];       // double-buffered hidden
    __shared__ __align__(16) float x_tile[2][16*I_]; // double-buffered 16-step x
    __shared__ float sums_lds[P_ * O_];              // 12 KB
    __shared__ float counts_lds[P_];                 // 4 KB

    // ---- weights -> named scalars (structurally un-spillable to arrays),
    //      pinned via asm so the loads can't be rematerialized in-loop ----
    const float4* wp0 = (const float4*)(W_hh + (0 * H_ + j) * H_ + kc * 32);
    const float4* wp1 = (const float4*)(W_hh + (1 * H_ + j) * H_ + kc * 32);
    const float4* wp2 = (const float4*)(W_hh + (2 * H_ + j) * H_ + kc * 32);
    const float4* wp3 = (const float4*)(W_hh + (3 * H_ + j) * H_ + kc * 32);
    #define WLOAD(g, n) float wx##g##_##n, wy##g##_##n, wz##g##_##n, ww##g##_##n; \
        { float4 t_ = wp##g[n]; wx##g##_##n = t_.x; wy##g##_##n = t_.y; \
          wz##g##_##n = t_.z; ww##g##_##n = t_.w; }
    FORALLW(WLOAD)
    #define WPIN(g, n) asm volatile( \
        "v_mov_b32 %0,%0\n\tv_mov_b32 %1,%1\n\tv_mov_b32 %2,%2\n\tv_mov_b32 %3,%3" \
        : "+v"(wx##g##_##n), "+v"(wy##g##_##n), "+v"(wz##g##_##n), "+v"(ww##g##_##n));
    FORALLW(WPIN)

    // W_ih: gate g, x-chunk [kc*4, kc*4+4)
    float4 u0 = *(const float4*)(W_ih + (0 * H_ + j) * I_ + kc * 4);
    float4 u1 = *(const float4*)(W_ih + (1 * H_ + j) * I_ + kc * 4);
    float4 u2 = *(const float4*)(W_ih + (2 * H_ + j) * I_ + kc * 4);
    float4 u3 = *(const float4*)(W_ih + (3 * H_ + j) * I_ + kc * 4);
    asm volatile("v_mov_b32 %0,%0\n\tv_mov_b32 %1,%1\n\tv_mov_b32 %2,%2\n\tv_mov_b32 %3,%3"
                 : "+v"(u0.x), "+v"(u0.y), "+v"(u0.z), "+v"(u0.w));
    asm volatile("v_mov_b32 %0,%0\n\tv_mov_b32 %1,%1\n\tv_mov_b32 %2,%2\n\tv_mov_b32 %3,%3"
                 : "+v"(u1.x), "+v"(u1.y), "+v"(u1.z), "+v"(u1.w));
    asm volatile("v_mov_b32 %0,%0\n\tv_mov_b32 %1,%1\n\tv_mov_b32 %2,%2\n\tv_mov_b32 %3,%3"
                 : "+v"(u2.x), "+v"(u2.y), "+v"(u2.z), "+v"(u2.w));
    asm volatile("v_mov_b32 %0,%0\n\tv_mov_b32 %1,%1\n\tv_mov_b32 %2,%2\n\tv_mov_b32 %3,%3"
                 : "+v"(u3.x), "+v"(u3.y), "+v"(u3.z), "+v"(u3.w));

    // this lane's OWN gate row is kc*128+j (lane kc activates gate kc)
    const float bias = b_ih[kc * H_ + j] + b_hh[kc * H_ + j];
    const float wfc  = (kc < 3) ? W_fc[kc * H_ + j] : 0.f;

    // ---- init LDS ----
    for (int i = tid; i < P_ * O_; i += 512) sums_lds[i] = 0.f;
    for (int i = tid; i < P_;      i += 512) counts_lds[i] = 0.f;
    if (tid < H_) h_s[0][tid] = 0.f;

    const float* xb = x + (size_t)b * T_ * I_;
    float4 xr4 = make_float4(0.f, 0.f, 0.f, 0.f);
    if (tid < 64) {                       // tile 0 = steps 0..15 (1 KB)
        xr4 = ((const float4*)xb)[tid];
        ((float4*)&x_tile[0][0])[tid] = xr4;
    }
    float c = 0.f;
    __syncthreads();

    #pragma unroll 1
    for (int t = 0; t < T_; ++t) {
        const int off = t & 15;
        const int btx = (t >> 4) & 1;
        const int bh  = t & 1;

        // x prefetch (wave 0 only): issue tile t+16 at off==0, commit to the
        // other LDS buffer at off==8 (8 steps of latency hiding)
        if (tid < 64) {
            if (off == 0 && t + 16 < T_)
                xr4 = ((const float4*)(xb + (t + 16) * I_))[tid];
            if (off == 8 && t + 8 < T_)
                ((float4*)&x_tile[btx ^ 1][0])[tid] = xr4;
        }

        const float4 xv = *(const float4*)&x_tile[btx][off * I_ + kc * 4];
        const int    id = (int)x_tile[btx][off * I_ + 2];   // broadcast b32

        // 4 gate-row partials over this thread's 32-wide h chunk
        float acc0 = 0.f, acc1 = 0.f, acc2 = 0.f, acc3 = 0.f;
        const float4* hc = (const float4*)&h_s[bh][kc * 32];
        #define HFMA(n) { float4 hv = hc[n]; \
            acc0 = fmaf(hv.x, wx0_##n, acc0); acc0 = fmaf(hv.y, wy0_##n, acc0); \
            acc0 = fmaf(hv.z, wz0_##n, acc0); acc0 = fmaf(hv.w, ww0_##n, acc0); \
            acc1 = fmaf(hv.x, wx1_##n, acc1); acc1 = fmaf(hv.y, wy1_##n, acc1); \
            acc1 = fmaf(hv.z, wz1_##n, acc1); acc1 = fmaf(hv.w, ww1_##n, acc1); \
            acc2 = fmaf(hv.x, wx2_##n, acc2); acc2 = fmaf(hv.y, wy2_##n, acc2); \
            acc2 = fmaf(hv.z, wz2_##n, acc2); acc2 = fmaf(hv.w, ww2_##n, acc2); \
            acc3 = fmaf(hv.x, wx3_##n, acc3); acc3 = fmaf(hv.y, wy3_##n, acc3); \
            acc3 = fmaf(hv.z, wz3_##n, acc3); acc3 = fmaf(hv.w, ww3_##n, acc3); }
        REP8(HFMA)
        // x contribution (chunked over kc as well)
        acc0 = fmaf(xv.x, u0.x, acc0); acc0 = fmaf(xv.y, u0.y, acc0);
        acc0 = fmaf(xv.z, u0.z, acc0); acc0 = fmaf(xv.w, u0.w, acc0);
        acc1 = fmaf(xv.x, u1.x, acc1); acc1 = fmaf(xv.y, u1.y, acc1);
        acc1 = fmaf(xv.z, u1.z, acc1); acc1 = fmaf(xv.w, u1.w, acc1);
        acc2 = fmaf(xv.x, u2.x, acc2); acc2 = fmaf(xv.y, u2.y, acc2);
        acc2 = fmaf(xv.z, u2.z, acc2); acc2 = fmaf(xv.w, u2.w, acc2);
        acc3 = fmaf(xv.x, u3.x, acc3); acc3 = fmaf(xv.y, u3.y, acc3);
        acc3 = fmaf(xv.z, u3.z, acc3); acc3 = fmaf(xv.w, u3.w, acc3);

        // quad butterfly (xor1=0xB1, xor2=0x4E): all 4 lanes get all 4 totals
        float s_;
        s_ = DPPF(acc0, 0xB1); acc0 += s_;
        s_ = DPPF(acc1, 0xB1); acc1 += s_;
        s_ = DPPF(acc2, 0xB1); acc2 += s_;
        s_ = DPPF(acc3, 0xB1); acc3 += s_;
        s_ = DPPF(acc0, 0x4E); acc0 += s_;
        s_ = DPPF(acc1, 0x4E); acc1 += s_;
        s_ = DPPF(acc2, 0x4E); acc2 += s_;
        s_ = DPPF(acc3, 0x4E); acc3 += s_;

        // lane kc activates gate kc (i,f,o sigmoid; g=kc==2 tanh), branchless
        float tg = (kc == 0) ? acc0 : (kc == 1) ? acc1 : (kc == 2) ? acc2 : acc3;
        tg += bias;
        const bool  isg = (kc == 2);
        const float arg = isg ? (tg + tg) : tg;
        const float sf  = 1.f / (1.f + __expf(-arg));
        const float act = isg ? (sf + sf - 1.f) : sf;   // tanh = 2*sig(2x)-1

        // gather the quad's 4 activated gates to every lane (quad_perm bcast)
        const float gi = DPPF(act, 0x00);
        const float gf = DPPF(act, 0x55);
        const float gg = DPPF(act, 0xAA);
        const float go = DPPF(act, 0xFF);
        c = fmaf(gf, c, gi * gg);            // c replicated across the quad
        const float hnew = go * tanh_f(c);

        if (kc == 0) h_s[bh ^ 1][j] = hnew;  // publish h_t (other buffer)

        // fused FC + segment accumulate with CURRENT step's h and id.
        // reduce over j within each 32-lane half (xor4,8,16), then LDS atomics.
        float p = hnew * wfc;
        p += SWZF(p, 0x101F);
        p += SWZF(p, 0x201F);
        p += SWZF(p, 0x401F);
        const bool idv = ((unsigned)id < P_);
        const int  l   = tid & 63;
        if (((l & 28) == 0) && kc < 3 && idv)
            atomicAdd(&sums_lds[id * O_ + kc], p);
        if (tid == 0 && idv)
            atomicAdd(&counts_lds[id], 1.f);

        lds_barrier();   // single barrier per step (h double-buffered)
    }

    // ---- writeback (block b owns slice b exclusively) ----
    float* sums_g = sums + (size_t)b * P_ * O_;
    for (int i = tid; i < P_ * O_; i += 512) sums_g[i] = sums_lds[i];
    float* cnt_g = counts + (size_t)b * P_;
    for (int i = tid; i < P_; i += 512) cnt_g[i] = counts_lds[i];
}

// out[b,p,o] = (sums[b,p,o] + cnt*b_fc[o]) / max(cnt,1)
__global__ void finalize_kernel(const float* __restrict__ sums,
                                const float* __restrict__ counts,
                                const float* __restrict__ b_fc,
                                float* __restrict__ out)
{
    const int idx = blockIdx.x * blockDim.x + threadIdx.x;
    if (idx >= B_ * P_ * O_) return;
    const int o  = idx % O_;
    const int bp = idx / O_;
    const float cnt = counts[bp];
    const float denom = (cnt > 0.f) ? cnt : 1.f;
    out[idx] = (sums[idx] + cnt * b_fc[o]) / denom;
}

extern "C" void kernel_launch(void* const* d_in, const int* in_sizes, int n_in,
                              void* d_out, int out_size, void* d_ws, size_t ws_size,
                              hipStream_t stream) {
    const float* x    = (const float*)d_in[0];
    const float* W_ih = (const float*)d_in[1];
    const float* W_hh = (const float*)d_in[2];
    const float* b_ih = (const float*)d_in[3];
    const float* b_hh = (const float*)d_in[4];
    const float* W_fc = (const float*)d_in[5];
    const float* b_fc = (const float*)d_in[6];
    // d_in[7] = num_photos (==P_, fixed by the problem)

    float* out    = (float*)d_out;
    float* sums   = (float*)d_ws;                 // B*P*3 floats
    float* counts = sums + (size_t)B_ * P_ * O_;  // B*P floats
    // sums/counts fully overwritten by lstm_fused — no memset needed.

    lstm_fused<<<B_, 512, 0, stream>>>(x, W_ih, W_hh, b_ih, b_hh, W_fc, sums, counts);

    const int n = B_ * P_ * O_;
    finalize_kernel<<<(n + 255) / 256, 256, 0, stream>>>(sums, counts, b_fc, out);
}

// Round 6
// 6357.368 us; speedup vs baseline: 2.3096x; 1.0809x over previous
//
#include <hip/hip_runtime.h>

// Problem constants (fixed by reference setup)
#define B_ 32
#define T_ 8192
#define I_ 16
#define H_ 128
#define P_ 1024
#define O_ 3

typedef _Float16 h2 __attribute__((ext_vector_type(2)));
typedef _Float16 h4 __attribute__((ext_vector_type(4)));
typedef _Float16 h8 __attribute__((ext_vector_type(8)));

// v_dot2_f32_f16: 2-way f16 dot, fp32 accumulate (CDNA dot insts)
#if __has_builtin(__builtin_amdgcn_fdot2)
#define FDOT2(a, b, c) __builtin_amdgcn_fdot2((a), (b), (c), false)
#else
__device__ __forceinline__ float fdot2_asm(h2 a, h2 b, float c) {
    asm("v_dot2_f32_f16 %0, %1, %2, %0" : "+v"(c) : "v"(a), "v"(b));
    return c;
}
#define FDOT2(a, b, c) fdot2_asm((a), (b), (c))
#endif

// ---- macro machinery: (gate g 0..3, m 0..3, e 0..3) ------------------------
#define FORME(M, g) M(g,0,0) M(g,0,1) M(g,0,2) M(g,0,3) \
                    M(g,1,0) M(g,1,1) M(g,1,2) M(g,1,3) \
                    M(g,2,0) M(g,2,1) M(g,2,2) M(g,2,3) \
                    M(g,3,0) M(g,3,1) M(g,3,2) M(g,3,3)
#define FORALL(M) FORME(M,0) FORME(M,1) FORME(M,2) FORME(M,3)
#define FORG(M) M(0) M(1) M(2) M(3)

// DPP quad-perm (kc lanes form quads): pure-VALU cross-lane.
#define DPPF(v, ctrl) \
    __int_as_float(__builtin_amdgcn_mov_dpp(__float_as_int(v), (ctrl), 0xF, 0xF, true))
// ds_swizzle xor-lane (BitMode): xor4=0x101F xor8=0x201F xor16=0x401F
#define SWZF(v, imm) \
    __int_as_float(__builtin_amdgcn_ds_swizzle(__float_as_int(v), (imm)))

__device__ __forceinline__ float tanh_f(float x) {
    return 2.f / (1.f + __expf(-2.f * x)) - 1.f;
}
__device__ __forceinline__ h4 cvt4(float4 v) {
    return (h4){(_Float16)v.x, (_Float16)v.y, (_Float16)v.z, (_Float16)v.w};
}

// LDS-only barrier: drain DS ops + s_barrier, without __syncthreads' vmcnt(0)
// drain (x-prefetch loads are consumed via register dependency).
__device__ __forceinline__ void lds_barrier() {
    asm volatile("s_waitcnt lgkmcnt(0)\n\ts_barrier" ::: "memory");
}

// One block per batch element. 512 threads, thread = (j, kc): j=unit 0..127,
// kc=quad lane 0..3. Thread covers 4 gate rows {g*128+j} x the f16 h-subset
// {kc*8+32m+e : m=0..3, e=0..7} (broadcast/conflict-free ds_read_b128s).
// Weights as f16 half2 in plain named scalars: 72 VGPRs total — small enough
// to FIT the ~88-reg budget the allocator has chosen in every prior round
// (R1-R4 showed it will not hold 144 fp32 regardless of pins/attributes;
// R5 showed VALU cannot source AGPRs). v_dot2_f32_f16 keeps fp32 accumulate;
// cell state c stays fp32; only h/x/weights quantize to f16.
__global__ __launch_bounds__(512, 2) __attribute__((amdgpu_waves_per_eu(2, 2)))
void lstm_fused(
    const float* __restrict__ x,      // [B,T,16]
    const float* __restrict__ W_ih,   // [512,16]
    const float* __restrict__ W_hh,   // [512,128]
    const float* __restrict__ b_ih,   // [512]
    const float* __restrict__ b_hh,   // [512]
    const float* __restrict__ W_fc,   // [3,128]
    float* __restrict__ sums,         // [B,P,3]  (fully overwritten per block)
    float* __restrict__ counts)       // [B,P]    (fully overwritten per block)
{
    const int b   = blockIdx.x;
    const int tid = threadIdx.x;
    const int j   = tid >> 2;
    const int kc  = tid & 3;

    __shared__ __align__(16) _Float16 hh[2][H_];       // hidden state, f16
    __shared__ __align__(16) _Float16 xt[2][16 * I_];  // x tile, f16
    __shared__ float sums_lds[P_ * O_];                // 12 KB
    __shared__ float counts_lds[P_];                   // 4 KB

    // ---- weights -> f16 half2 named scalars (64 + 8 = 72 VGPRs) ----
    const float* wr0 = W_hh + (0 * H_ + j) * H_;
    const float* wr1 = W_hh + (1 * H_ + j) * H_;
    const float* wr2 = W_hh + (2 * H_ + j) * H_;
    const float* wr3 = W_hh + (3 * H_ + j) * H_;
    // slot (g,m,e) holds W_hh[g*128+j][kc*8+32m+2e .. +1]
    #define WLOAD(g, m, e) h2 W##g##_##m##_##e = (h2){ \
        (_Float16)wr##g[kc * 8 + 32 * (m) + 2 * (e)], \
        (_Float16)wr##g[kc * 8 + 32 * (m) + 2 * (e) + 1]};
    FORALL(WLOAD)

    // W_ih: gate g, x-chunk [kc*4, kc*4+4) as 2 half2
    #define ULOAD(g) \
        h2 U##g##_0 = (h2){(_Float16)W_ih[((g) * H_ + j) * I_ + kc * 4 + 0], \
                           (_Float16)W_ih[((g) * H_ + j) * I_ + kc * 4 + 1]}; \
        h2 U##g##_1 = (h2){(_Float16)W_ih[((g) * H_ + j) * I_ + kc * 4 + 2], \
                           (_Float16)W_ih[((g) * H_ + j) * I_ + kc * 4 + 3]};
    FORG(ULOAD)

    // lane kc activates gate kc: its own row is kc*128+j
    const float bias = b_ih[kc * H_ + j] + b_hh[kc * H_ + j];
    const float wfc  = (kc < 3) ? W_fc[kc * H_ + j] : 0.f;

    // ---- init LDS ----
    for (int i = tid; i < P_ * O_; i += 512) sums_lds[i] = 0.f;
    for (int i = tid; i < P_;      i += 512) counts_lds[i] = 0.f;
    if (tid < H_) hh[0][tid] = (_Float16)0.f;

    const float* xb = x + (size_t)b * T_ * I_;
    float4 xr4 = make_float4(0.f, 0.f, 0.f, 0.f);
    if (tid < 64) {                       // tile 0 = steps 0..15
        xr4 = ((const float4*)xb)[tid];
        *(h4*)&xt[0][tid * 4] = cvt4(xr4);
    }
    float c = 0.f;
    __syncthreads();

    #pragma unroll 1
    for (int t = 0; t < T_; ++t) {
        const int off = t & 15;
        const int btx = (t >> 4) & 1;
        const int bh  = t & 1;

        // x prefetch (wave 0): issue tile t+16 at off==0, commit at off==8
        if (tid < 64) {
            if (off == 0 && t + 16 < T_)
                xr4 = ((const float4*)(xb + (t + 16) * I_))[tid];
            if (off == 8 && t + 8 < T_)
                *(h4*)&xt[btx ^ 1][tid * 4] = cvt4(xr4);
        }

        const h4 xv4 = *(const h4*)&xt[btx][off * I_ + kc * 4];
        const h2 xv0 = __builtin_shufflevector(xv4, xv4, 0, 1);
        const h2 xv1 = __builtin_shufflevector(xv4, xv4, 2, 3);
        const int id = (int)(float)xt[btx][off * I_ + 2];   // exact (id<2048)

        // 4 gate-row partials over this thread's 32-float h subset (f16 dots)
        float acc0 = 0.f, acc1 = 0.f, acc2 = 0.f, acc3 = 0.f;
        #define HD(m) { \
            h8 hv = *(const h8*)&hh[bh][kc * 8 + 32 * (m)]; \
            h2 p0 = __builtin_shufflevector(hv, hv, 0, 1); \
            h2 p1 = __builtin_shufflevector(hv, hv, 2, 3); \
            h2 p2 = __builtin_shufflevector(hv, hv, 4, 5); \
            h2 p3 = __builtin_shufflevector(hv, hv, 6, 7); \
            acc0 = FDOT2(p0, W0_##m##_0, acc0); acc0 = FDOT2(p1, W0_##m##_1, acc0); \
            acc0 = FDOT2(p2, W0_##m##_2, acc0); acc0 = FDOT2(p3, W0_##m##_3, acc0); \
            acc1 = FDOT2(p0, W1_##m##_0, acc1); acc1 = FDOT2(p1, W1_##m##_1, acc1); \
            acc1 = FDOT2(p2, W1_##m##_2, acc1); acc1 = FDOT2(p3, W1_##m##_3, acc1); \
            acc2 = FDOT2(p0, W2_##m##_0, acc2); acc2 = FDOT2(p1, W2_##m##_1, acc2); \
            acc2 = FDOT2(p2, W2_##m##_2, acc2); acc2 = FDOT2(p3, W2_##m##_3, acc2); \
            acc3 = FDOT2(p0, W3_##m##_0, acc3); acc3 = FDOT2(p1, W3_##m##_1, acc3); \
            acc3 = FDOT2(p2, W3_##m##_2, acc3); acc3 = FDOT2(p3, W3_##m##_3, acc3); }
        HD(0) HD(1) HD(2) HD(3)
        // x contribution
        acc0 = FDOT2(xv0, U0_0, acc0); acc0 = FDOT2(xv1, U0_1, acc0);
        acc1 = FDOT2(xv0, U1_0, acc1); acc1 = FDOT2(xv1, U1_1, acc1);
        acc2 = FDOT2(xv0, U2_0, acc2); acc2 = FDOT2(xv1, U2_1, acc2);
        acc3 = FDOT2(xv0, U3_0, acc3); acc3 = FDOT2(xv1, U3_1, acc3);

        // quad butterfly (xor1=0xB1, xor2=0x4E): all 4 lanes get all 4 totals
        float s_;
        s_ = DPPF(acc0, 0xB1); acc0 += s_;
        s_ = DPPF(acc1, 0xB1); acc1 += s_;
        s_ = DPPF(acc2, 0xB1); acc2 += s_;
        s_ = DPPF(acc3, 0xB1); acc3 += s_;
        s_ = DPPF(acc0, 0x4E); acc0 += s_;
        s_ = DPPF(acc1, 0x4E); acc1 += s_;
        s_ = DPPF(acc2, 0x4E); acc2 += s_;
        s_ = DPPF(acc3, 0x4E); acc3 += s_;

        // lane kc activates gate kc (i,f,o sigmoid; g=kc==2 tanh), branchless
        float tg = (kc == 0) ? acc0 : (kc == 1) ? acc1 : (kc == 2) ? acc2 : acc3;
        tg += bias;
        const bool  isg = (kc == 2);
        const float arg = isg ? (tg + tg) : tg;
        const float sf  = 1.f / (1.f + __expf(-arg));
        const float act = isg ? (sf + sf - 1.f) : sf;   // tanh = 2*sig(2x)-1

        // gather the quad's 4 activated gates (quad_perm broadcasts)
        const float gi = DPPF(act, 0x00);
        const float gf = DPPF(act, 0x55);
        const float gg = DPPF(act, 0xAA);
        const float go = DPPF(act, 0xFF);
        c = fmaf(gf, c, gi * gg);            // c replicated across the quad (fp32)
        const float hnew = go * tanh_f(c);

        if (kc == 0) hh[bh ^ 1][j] = (_Float16)hnew;   // publish h_t (f16)

        // fused FC + segment accumulate (fp32 hnew): reduce the wave's 16 j
        // (xor4,8,16 swizzle + xor32 shfl) -> 3 LDS atomics per wave
        float p = hnew * wfc;
        p += SWZF(p, 0x101F);
        p += SWZF(p, 0x201F);
        p += SWZF(p, 0x401F);
        p += __shfl_xor(p, 32, 64);
        const bool idv = ((unsigned)id < P_);
        if (((tid & 63) < 3) && idv)
            atomicAdd(&sums_lds[id * O_ + (tid & 63)], p);
        if (tid == 0 && idv)
            atomicAdd(&counts_lds[id], 1.f);

        lds_barrier();   // single barrier per step (h double-buffered)
    }

    // ---- writeback (block b owns slice b exclusively) ----
    float* sums_g = sums + (size_t)b * P_ * O_;
    for (int i = tid; i < P_ * O_; i += 512) sums_g[i] = sums_lds[i];
    float* cnt_g = counts + (size_t)b * P_;
    for (int i = tid; i < P_; i += 512) cnt_g[i] = counts_lds[i];
}

// out[b,p,o] = (sums[b,p,o] + cnt*b_fc[o]) / max(cnt,1)
__global__ void finalize_kernel(const float* __restrict__ sums,
                                const float* __restrict__ counts,
                                const float* __restrict__ b_fc,
                                float* __restrict__ out)
{
    const int idx = blockIdx.x * blockDim.x + threadIdx.x;
    if (idx >= B_ * P_ * O_) return;
    const int o  = idx % O_;
    const int bp = idx / O_;
    const float cnt = counts[bp];
    const float denom = (cnt > 0.f) ? cnt : 1.f;
    out[idx] = (sums[idx] + cnt * b_fc[o]) / denom;
}

extern "C" void kernel_launch(void* const* d_in, const int* in_sizes, int n_in,
                              void* d_out, int out_size, void* d_ws, size_t ws_size,
                              hipStream_t stream) {
    const float* x    = (const float*)d_in[0];
    const float* W_ih = (const float*)d_in[1];
    const float* W_hh = (const float*)d_in[2];
    const float* b_ih = (const float*)d_in[3];
    const float* b_hh = (const float*)d_in[4];
    const float* W_fc = (const float*)d_in[5];
    const float* b_fc = (const float*)d_in[6];
    // d_in[7] = num_photos (==P_, fixed by the problem)

    float* out    = (float*)d_out;
    float* sums   = (float*)d_ws;                 // B*P*3 floats
    float* counts = sums + (size_t)B_ * P_ * O_;  // B*P floats
    // sums/counts fully overwritten by lstm_fused — no memset needed.

    lstm_fused<<<B_, 512, 0, stream>>>(x, W_ih, W_hh, b_ih, b_hh, W_fc, sums, counts);

    const int n = B_ * P_ * O_;
    finalize_kernel<<<(n + 255) / 256, 256, 0, stream>>>(sums, counts, b_fc, out);
}